// Round 3
// baseline (1129.232 us; speedup 1.0000x reference)
//
#include <hip/hip_runtime.h>

#define C 512
#define HW 4096
#define EPSV 1e-5f

typedef _Float16 fp16x8 __attribute__((ext_vector_type(8)));
typedef _Float16 fp16x4 __attribute__((ext_vector_type(4)));
typedef float f32x4 __attribute__((ext_vector_type(4)));

// ---- workspace layout (bytes) ----
#define OFF_MC    (0)
#define OFF_RC    (8192)
#define OFF_MS    (16384)
#define OFF_RS    (24576)
#define OFF_BETAF (32768)
#define OFF_V     (40960)
#define OFF_BZ    (49152)
#define OFF_A     (65536)
#define OFF_WZ    (OFF_A + 1048576)
#define OFF_T     (OFF_WZ + 1048576)
#define OFF_XCT   (OFF_T + 65536)
#define OFF_XST   (OFF_XCT + 16777216)
#define OFF_KT    (OFF_XST + 16777216)
#define OFF_HM    (OFF_KT + 16777216)
#define OFF_ML    (OFF_HM + 16777216)      // [2 split][4 b][4096 n] float2 = 256 KB
#define OFF_OP1   (OFF_ML + 262144)        // split-1 partial O, f32 [4][512][4096] = 32 MB
// total ~= 101.6 MB   (split-0 partial O lives in d_out)

// ---------------------------------------------------------------------------
// 1) per-(b,c) mean / rstd for content (tensor 0) and style (tensor 1)
// ---------------------------------------------------------------------------
__global__ void stats_kernel(const float* __restrict__ xc, const float* __restrict__ xs,
                             char* __restrict__ ws)
{
    int idx = blockIdx.x;                 // 4096 = 2 * 4 * 512
    int tensor = idx >> 11, rem = idx & 2047;
    const float* src = tensor ? xs : xc;
    float* mean = (float*)(ws + (tensor ? OFF_MS : OFF_MC));
    float* rstd = (float*)(ws + (tensor ? OFF_RS : OFF_RC));
    const float* p = src + (size_t)rem * HW;
    float s = 0.f, ss = 0.f;
    for (int i = threadIdx.x; i < HW; i += 256) { float v = p[i]; s += v; ss += v * v; }
    #pragma unroll
    for (int off = 32; off > 0; off >>= 1) { s += __shfl_down(s, off); ss += __shfl_down(ss, off); }
    __shared__ float red[8];
    int w = threadIdx.x >> 6;
    if ((threadIdx.x & 63) == 0) { red[w * 2] = s; red[w * 2 + 1] = ss; }
    __syncthreads();
    if (threadIdx.x == 0) {
        s = red[0] + red[2] + red[4] + red[6];
        ss = red[1] + red[3] + red[5] + red[7];
        float m = s / (float)HW;
        float var = (ss - s * m) / (float)(HW - 1) + EPSV;   // unbiased (n-1) + EPS
        mean[rem] = m;
        rstd[rem] = rsqrtf(var);
    }
}

// ---------------------------------------------------------------------------
// 2) transpose + f16 cast:  x[b][c][n] (fp32) -> xT[b][n][c] (f16)
// ---------------------------------------------------------------------------
__global__ void transpose_kernel(const float* __restrict__ xc, const float* __restrict__ xs,
                                 char* __restrict__ ws)
{
    int bx = blockIdx.x;                  // 4096 = 2 * 4 * 8 * 64
    int tensor = bx >> 11, b = (bx >> 9) & 3, c0 = ((bx >> 6) & 7) * 64, n0 = (bx & 63) * 64;
    const float* src = tensor ? xs : xc;
    _Float16* dst = (_Float16*)(ws + (tensor ? OFF_XST : OFF_XCT));
    __shared__ _Float16 tile[64][66];
    #pragma unroll
    for (int i = 0; i < 16; i++) {
        int flat = threadIdx.x + i * 256;
        int cR = flat >> 6, nR = flat & 63;
        tile[nR][cR] = (_Float16)src[((size_t)(b * C + c0 + cR)) * HW + n0 + nR];
    }
    __syncthreads();
    #pragma unroll
    for (int i = 0; i < 16; i++) {
        int flat = threadIdx.x + i * 256;
        int nW = flat >> 6, cW = flat & 63;
        dst[((size_t)(b * HW + n0 + nW)) * C + c0 + cW] = tile[nW][cW];
    }
}

// ---------------------------------------------------------------------------
// 3) small precomputes: A = Wf^T Wg, Wz = Wo Wh, betaf, bz = Wo bh
//    grid 522: [0,256) A 2 rows each; [256,512) Wz 2 rows; [512,520) betaf; [520,522) bz
// ---------------------------------------------------------------------------
__global__ void precompute_kernel(const float* __restrict__ Wf, const float* __restrict__ Wg,
                                  const float* __restrict__ Wo, const float* __restrict__ Wh,
                                  const float* __restrict__ bf, const float* __restrict__ bh,
                                  char* __restrict__ ws)
{
    float* A = (float*)(ws + OFF_A);
    float* Wz = (float*)(ws + OFF_WZ);
    float* betaf = (float*)(ws + OFF_BETAF);
    float* bz = (float*)(ws + OFF_BZ);
    const float* mc = (const float*)(ws + OFF_MC);
    const float* rc = (const float*)(ws + OFF_RC);
    int bx = blockIdx.x, t = threadIdx.x;
    if (bx < 512) {                              // A or Wz, 2 output rows per block
        bool isA = bx < 256;
        int r0 = (isA ? bx : bx - 256) * 2;
        const float* L = isA ? Wf : 0;
        float a00 = 0.f, a01 = 0.f, a10 = 0.f, a11 = 0.f;
        for (int k = 0; k < C; k++) {
            float r0v, r1v, c0v, c1v;
            if (isA) {                           // A[i][j] = sum_co Wf[co][i]*Wg[co][j]
                r0v = Wf[k * C + r0]; r1v = Wf[k * C + r0 + 1];
                c0v = Wg[k * C + t];  c1v = Wg[k * C + t + 256];
            } else {                             // Wz[o][j] = sum_i Wo[o][i]*Wh[i][j]
                r0v = Wo[r0 * C + k]; r1v = Wo[(r0 + 1) * C + k];
                c0v = Wh[k * C + t];  c1v = Wh[k * C + t + 256];
            }
            a00 += r0v * c0v; a01 += r0v * c1v;
            a10 += r1v * c0v; a11 += r1v * c1v;
        }
        float* D = isA ? A : Wz;
        D[r0 * C + t] = a00;       D[r0 * C + t + 256] = a01;
        D[(r0 + 1) * C + t] = a10; D[(r0 + 1) * C + t + 256] = a11;
        (void)L;
    } else if (bx < 520) {                       // betaf[b][co] = bf[co] - sum_i Wf[co][i]*mc*rc
        int g = (bx - 512) * 256 + t, b = g >> 9, co = g & 511;
        float acc = 0.f;
        for (int i = 0; i < C; i++) acc += Wf[co * C + i] * mc[b * C + i] * rc[b * C + i];
        betaf[g] = bf[co] - acc;
    } else {                                     // bz[co] = sum_i Wo[co][i]*bh[i]
        int co = (bx - 520) * 256 + t;
        float acc = 0.f;
        for (int i = 0; i < C; i++) acc += Wo[co * C + i] * bh[i];
        bz[co] = acc;
    }
}

// v[b][j] = rs[b][j] * sum_co betaf[b][co]*Wg[co][j]   (64 blocks, 8 lanes/output)
__global__ void precompute_v_kernel(const float* __restrict__ Wg, char* __restrict__ ws)
{
    const float* betaf = (const float*)(ws + OFF_BETAF);
    const float* rs = (const float*)(ws + OFF_RS);
    float* v = (float*)(ws + OFF_V);
    int g = blockIdx.x * 32 + (threadIdx.x >> 3);   // 0..2047 output index
    int b = g >> 9, j = g & 511, cq = threadIdx.x & 7;
    float acc = 0.f;
    for (int co = cq * 64; co < cq * 64 + 64; co++) acc += betaf[b * C + co] * Wg[co * C + j];
    acc += __shfl_xor(acc, 1);
    acc += __shfl_xor(acc, 2);
    acc += __shfl_xor(acc, 4);
    if (cq == 0) v[g] = rs[b * C + j] * acc;
}

// ---------------------------------------------------------------------------
// 4) fused prep GEMM:
//    rows 0..511   : Kt[b][m][c] = (diag(rc) A diag(rs) @ xs)[c][m]   (stored transposed, f16)
//    rows 512..1023: Hm[b][co][m] = (Wz @ xs)[co][m] + bz[co]         (f16)
// ---------------------------------------------------------------------------
__global__ void __launch_bounds__(256) prep_gemm_kernel(char* __restrict__ ws)
{
    const float* A = (const float*)(ws + OFF_A);
    const float* Wz = (const float*)(ws + OFF_WZ);
    const float* rc = (const float*)(ws + OFF_RC);
    const float* rs = (const float*)(ws + OFF_RS);
    const float* bz = (const float*)(ws + OFF_BZ);
    const _Float16* __restrict__ xsT = (const _Float16*)(ws + OFF_XST);
    _Float16* __restrict__ Kt = (_Float16*)(ws + OFF_KT);
    _Float16* __restrict__ Hm = (_Float16*)(ws + OFF_HM);

    int bx = blockIdx.x;                 // 1024 = 4b * 8 rowblk * 32 mblk (XCD-swizzled)
    int b = bx & 3, rest = bx >> 2;
    int r128 = rest >> 5, mb = rest & 31;
    int r0 = r128 * 128, m0 = mb * 128;
    int w = threadIdx.x >> 6, lane = threadIdx.x & 63, q = lane >> 4, l16 = lane & 15;
    int wr = (w & 1) * 64, wm = (w >> 1) * 64;
    bool isK = (r0 < 512);
    const float* Asrc = isK ? A : Wz;
    int rbase = (isK ? r0 : r0 - 512) + wr;

    f32x4 zz = {0.f, 0.f, 0.f, 0.f};
    f32x4 acc[4][4];
    #pragma unroll
    for (int rt = 0; rt < 4; rt++)
        #pragma unroll
        for (int mt = 0; mt < 4; mt++) acc[rt][mt] = zz;

    float rcv[4];
    #pragma unroll
    for (int rt = 0; rt < 4; rt++)
        rcv[rt] = isK ? rc[b * C + rbase + rt * 16 + l16] : 1.f;

    for (int ks = 0; ks < 16; ks++) {
        int j0 = ks * 32 + q * 8;
        float rsv[8];
        if (isK) {
            float4 u0 = *(const float4*)&rs[b * C + j0];
            float4 u1 = *(const float4*)&rs[b * C + j0 + 4];
            rsv[0] = u0.x; rsv[1] = u0.y; rsv[2] = u0.z; rsv[3] = u0.w;
            rsv[4] = u1.x; rsv[5] = u1.y; rsv[6] = u1.z; rsv[7] = u1.w;
        } else {
            #pragma unroll
            for (int jj = 0; jj < 8; jj++) rsv[jj] = 1.f;
        }
        fp16x8 afr[4];
        #pragma unroll
        for (int rt = 0; rt < 4; rt++) {
            int row = rbase + rt * 16 + l16;
            float4 a0 = *(const float4*)&Asrc[row * C + j0];
            float4 a1 = *(const float4*)&Asrc[row * C + j0 + 4];
            float av8[8];
            av8[0] = a0.x; av8[1] = a0.y; av8[2] = a0.z; av8[3] = a0.w;
            av8[4] = a1.x; av8[5] = a1.y; av8[6] = a1.z; av8[7] = a1.w;
            float sc = rcv[rt];
            #pragma unroll
            for (int jj = 0; jj < 8; jj++)
                afr[rt][jj] = (_Float16)(isK ? av8[jj] * sc * rsv[jj] : av8[jj]);
        }
        fp16x8 bfr[4];
        #pragma unroll
        for (int mt = 0; mt < 4; mt++)
            bfr[mt] = *(const fp16x8*)&xsT[((size_t)(b * HW + m0 + wm + mt * 16 + l16)) * C + j0];
        #pragma unroll
        for (int rt = 0; rt < 4; rt++)
            #pragma unroll
            for (int mt = 0; mt < 4; mt++)
                acc[rt][mt] = __builtin_amdgcn_mfma_f32_16x16x32_f16(afr[rt], bfr[mt], acc[rt][mt], 0, 0, 0);
    }

    if (isK) {
        #pragma unroll
        for (int rt = 0; rt < 4; rt++)
            #pragma unroll
            for (int mt = 0; mt < 4; mt++) {
                int m = m0 + wm + mt * 16 + l16;
                int cb = r0 + wr + rt * 16 + q * 4;
                fp16x4 h;
                h[0] = (_Float16)acc[rt][mt][0]; h[1] = (_Float16)acc[rt][mt][1];
                h[2] = (_Float16)acc[rt][mt][2]; h[3] = (_Float16)acc[rt][mt][3];
                *(fp16x4*)&Kt[((size_t)(b * HW + m)) * C + cb] = h;
            }
    } else {
        #pragma unroll
        for (int rt = 0; rt < 4; rt++) {
            float bzv[4];
            #pragma unroll
            for (int reg = 0; reg < 4; reg++) bzv[reg] = bz[rbase + rt * 16 + q * 4 + reg];
            #pragma unroll
            for (int mt = 0; mt < 4; mt++) {
                int m = m0 + wm + mt * 16 + l16;
                #pragma unroll
                for (int reg = 0; reg < 4; reg++) {
                    int co = rbase + rt * 16 + q * 4 + reg;
                    Hm[((size_t)(b * C + co)) * HW + m] = (_Float16)(acc[rt][mt][reg] + bzv[reg]);
                }
            }
        }
    }
}

// ---------------------------------------------------------------------------
// 5) t[b][m] = sum_j v[b][j] * xsT[b][m][j]   (per-key softmax bias, f16 source)
// ---------------------------------------------------------------------------
__global__ void t_kernel(char* __restrict__ ws)
{
    const float* v = (const float*)(ws + OFF_V);
    const _Float16* __restrict__ xsT = (const _Float16*)(ws + OFF_XST);
    float* tG = (float*)(ws + OFF_T);
    int bx = blockIdx.x;                      // 512 = 4 b * 128 mchunks(32)
    int b = bx >> 7, m0 = (bx & 127) * 32;
    int m = m0 + (threadIdx.x >> 3), cq = threadIdx.x & 7;
    const _Float16* p = xsT + ((size_t)(b * HW + m)) * C + cq * 64;
    const float* vp = v + b * C + cq * 64;
    float acc = 0.f;
    #pragma unroll
    for (int k = 0; k < 8; k++) {
        fp16x8 xv = *(const fp16x8*)(p + k * 8);
        float4 v0 = *(const float4*)(vp + k * 8);
        float4 v1 = *(const float4*)(vp + k * 8 + 4);
        acc += (float)xv[0] * v0.x + (float)xv[1] * v0.y + (float)xv[2] * v0.z + (float)xv[3] * v0.w
             + (float)xv[4] * v1.x + (float)xv[5] * v1.y + (float)xv[6] * v1.z + (float)xv[7] * v1.w;
    }
    acc += __shfl_xor(acc, 1);
    acc += __shfl_xor(acc, 2);
    acc += __shfl_xor(acc, 4);
    if (cq == 0) tG[b * HW + m] = acc;
}

// ---------------------------------------------------------------------------
// 6) split-K flash attention (2 splits of 2048 keys). Writes UNNORMALIZED
//    partial O (split0 -> d_out, split1 -> ws) + per-row (max, sumexp).
//    Swizzle: bx = n_idx*8 + (s*4+b) -> each XCD owns one (b,s): 4 MB L2 set.
//    Per iter: QK direct-L2 frags, H frags hoisted pre-barrier, 8-lane softmax.
// ---------------------------------------------------------------------------
__global__ void __launch_bounds__(256, 3) flash_split_kernel(float* __restrict__ out0,
                                                             char* __restrict__ ws)
{
    const _Float16* __restrict__ xcT = (const _Float16*)(ws + OFF_XCT);
    const _Float16* __restrict__ Kt = (const _Float16*)(ws + OFF_KT);
    const _Float16* __restrict__ Hm = (const _Float16*)(ws + OFF_HM);
    const float* __restrict__ tG = (const float*)(ws + OFF_T);
    float2* __restrict__ ML = (float2*)(ws + OFF_ML);
    float* __restrict__ out1 = (float*)(ws + OFF_OP1);

    int bx = blockIdx.x;                  // 1024 = 128 n-idx * (2 s * 4 b)
    int b = bx & 3, s = (bx >> 2) & 1, n0 = (bx >> 3) * 32;
    int tid = threadIdx.x, w = tid >> 6, lane = tid & 63, q = lane >> 4, l16 = lane & 15;

    __shared__ _Float16 Qs[32][520];
    __shared__ float Ls[32][68];
    __shared__ _Float16 Ps[2][32][72];
    __shared__ float alphaS[2][32];

    // stage Q[32][512] f16 once
    #pragma unroll
    for (int i = 0; i < 8; i++) {
        int g = tid + i * 256;
        int row = g >> 6, ch = g & 63;
        *(fp16x8*)&Qs[row][ch * 8] = *(const fp16x8*)&xcT[((size_t)(b * HW + n0 + row)) * C + ch * 8];
    }
    __syncthreads();

    f32x4 zz = {0.f, 0.f, 0.f, 0.f};
    f32x4 acc[2][8];
    #pragma unroll
    for (int nt = 0; nt < 2; nt++)
        #pragma unroll
        for (int ct = 0; ct < 8; ct++) acc[nt][ct] = zz;

    int co0 = w * 128, nt_s = (w & 1) * 16, mh = (w >> 1) * 32;
    const _Float16* kbase = Kt + ((size_t)(b * HW + mh + l16)) * C;   // + (m0+mi*16)*C + k
    const _Float16* hbase = Hm + ((size_t)(b * C + co0 + l16)) * HW;  // + ct*16*HW + m0 + kk
    const _Float16* qrow = &Qs[nt_s + l16][0];

    int srow = tid >> 3, skg = tid & 7;       // softmax: 8 lanes per query row
    float mx = -3.0e38f, sm = 0.f;            // row-replicated running state

    for (int it = s * 32; it < s * 32 + 32; it++) {
        int m0 = it * 64, buf = it & 1;

        // ---- QK: B-frags straight from L2-resident Kt ----
        f32x4 Lf[2];
        Lf[0] = zz; Lf[1] = zz;
        #pragma unroll 4
        for (int ks = 0; ks < 16; ks++) {
            int k = ks * 32 + q * 8;
            fp16x8 afr = *(const fp16x8*)(qrow + k);
            fp16x8 b0 = *(const fp16x8*)(kbase + (size_t)m0 * C + k);
            fp16x8 b1 = *(const fp16x8*)(kbase + (size_t)(m0 + 16) * C + k);
            Lf[0] = __builtin_amdgcn_mfma_f32_16x16x32_f16(afr, b0, Lf[0], 0, 0, 0);
            Lf[1] = __builtin_amdgcn_mfma_f32_16x16x32_f16(afr, b1, Lf[1], 0, 0, 0);
        }

        // ---- hoist H-frag loads for this iter (independent of softmax) ----
        fp16x8 hfr[16];
        #pragma unroll
        for (int ct = 0; ct < 8; ct++)
            #pragma unroll
            for (int ksi = 0; ksi < 2; ksi++)
                hfr[ct * 2 + ksi] =
                    *(const fp16x8*)(hbase + (size_t)ct * 16 * HW + m0 + ksi * 32 + q * 8);

        // spill logits (C-layout: col=l16 -> m, row=q*4+reg -> n)
        #pragma unroll
        for (int mi = 0; mi < 2; mi++)
            #pragma unroll
            for (int reg = 0; reg < 4; reg++)
                Ls[nt_s + q * 4 + reg][mh + mi * 16 + l16] = Lf[mi][reg];
        __syncthreads();

        // ---- online softmax: 8 lanes per row, 8 keys each ----
        float4 la = *(const float4*)&Ls[srow][skg * 8];
        float4 lb = *(const float4*)&Ls[srow][skg * 8 + 4];
        float4 ta = *(const float4*)&tG[b * HW + m0 + skg * 8];
        float4 tb = *(const float4*)&tG[b * HW + m0 + skg * 8 + 4];
        float l[8];
        l[0] = la.x + ta.x; l[1] = la.y + ta.y; l[2] = la.z + ta.z; l[3] = la.w + ta.w;
        l[4] = lb.x + tb.x; l[5] = lb.y + tb.y; l[6] = lb.z + tb.z; l[7] = lb.w + tb.w;
        float lmax = fmaxf(fmaxf(fmaxf(l[0], l[1]), fmaxf(l[2], l[3])),
                           fmaxf(fmaxf(l[4], l[5]), fmaxf(l[6], l[7])));
        lmax = fmaxf(lmax, __shfl_xor(lmax, 1));
        lmax = fmaxf(lmax, __shfl_xor(lmax, 2));
        lmax = fmaxf(lmax, __shfl_xor(lmax, 4));
        float mxn = fmaxf(mx, lmax);
        float alpha = __expf(mx - mxn);
        float ssum = 0.f;
        fp16x8 ph;
        #pragma unroll
        for (int jj = 0; jj < 8; jj++) {
            float p = __expf(l[jj] - mxn);
            ph[jj] = (_Float16)p;
            ssum += p;
        }
        ssum += __shfl_xor(ssum, 1);
        ssum += __shfl_xor(ssum, 2);
        ssum += __shfl_xor(ssum, 4);
        sm = sm * alpha + ssum;
        mx = mxn;
        *(fp16x8*)&Ps[buf][srow][skg * 8] = ph;
        if (skg == 0) alphaS[buf][srow] = alpha;
        __syncthreads();

        // ---- rescale + PV (H frags already in registers) ----
        float av[2][4];
        #pragma unroll
        for (int nt = 0; nt < 2; nt++)
            #pragma unroll
            for (int reg = 0; reg < 4; reg++) av[nt][reg] = alphaS[buf][nt * 16 + q * 4 + reg];
        #pragma unroll
        for (int nt = 0; nt < 2; nt++)
            #pragma unroll
            for (int ct = 0; ct < 8; ct++)
                #pragma unroll
                for (int reg = 0; reg < 4; reg++) acc[nt][ct][reg] *= av[nt][reg];
        #pragma unroll
        for (int ksi = 0; ksi < 2; ksi++) {
            int kk = ksi * 32 + q * 8;
            fp16x8 a0 = *(const fp16x8*)&Ps[buf][l16][kk];
            fp16x8 a1 = *(const fp16x8*)&Ps[buf][16 + l16][kk];
            #pragma unroll
            for (int ct = 0; ct < 8; ct++) {
                acc[0][ct] = __builtin_amdgcn_mfma_f32_16x16x32_f16(a0, hfr[ct * 2 + ksi], acc[0][ct], 0, 0, 0);
                acc[1][ct] = __builtin_amdgcn_mfma_f32_16x16x32_f16(a1, hfr[ct * 2 + ksi], acc[1][ct], 0, 0, 0);
            }
        }
    }

    // per-row (max, sumexp) for the combine pass
    if (skg == 0) ML[((size_t)(s * 4 + b)) * HW + n0 + srow] = make_float2(mx, sm);

    float* dst = s ? out1 : out0;
    #pragma unroll
    for (int nt = 0; nt < 2; nt++)
        #pragma unroll
        for (int ct = 0; ct < 8; ct++) {
            int co = co0 + ct * 16 + l16;
            size_t base = ((size_t)(b * C + co)) * HW + n0 + nt * 16 + q * 4;
            *(f32x4*)&dst[base] = acc[nt][ct];
        }
}

// ---------------------------------------------------------------------------
// 7) combine: out = (O0*e0 + O1*e1) / (l0*e0 + l1*e1) + bo + content
// ---------------------------------------------------------------------------
__global__ void combine_kernel(const float* __restrict__ xc, const float* __restrict__ bo,
                               float* __restrict__ out, char* __restrict__ ws)
{
    const float2* __restrict__ ML = (const float2*)(ws + OFF_ML);
    const float* __restrict__ O1 = (const float*)(ws + OFF_OP1);
    int bx = blockIdx.x;                      // 256 = 4 b * 64 nchunks(64)
    int b = bx >> 6, n0 = (bx & 63) * 64;
    int tid = threadIdx.x;

    __shared__ float a0s[64], a1s[64];
    if (tid < 64) {
        float2 p0 = ML[(size_t)b * HW + n0 + tid];
        float2 p1 = ML[((size_t)(4 + b)) * HW + n0 + tid];
        float M = fmaxf(p0.x, p1.x);
        float e0 = __expf(p0.x - M), e1 = __expf(p1.x - M);
        float linv = 1.f / (p0.y * e0 + p1.y * e1);
        a0s[tid] = e0 * linv;
        a1s[tid] = e1 * linv;
    }
    __syncthreads();

    int nq = (tid & 15) * 4, cof = tid >> 4;
    float4 s0 = *(const float4*)&a0s[nq];
    float4 s1 = *(const float4*)&a1s[nq];
    for (int itc = 0; itc < 32; itc++) {
        int co = itc * 16 + cof;
        size_t base = ((size_t)(b * C + co)) * HW + n0 + nq;
        float4 o0 = *(const float4*)&out[base];
        float4 o1 = *(const float4*)&O1[base];
        float4 cv = *(const float4*)&xc[base];
        float bov = bo[co];
        float4 o;
        o.x = o0.x * s0.x + o1.x * s1.x + bov + cv.x;
        o.y = o0.y * s0.y + o1.y * s1.y + bov + cv.y;
        o.z = o0.z * s0.z + o1.z * s1.z + bov + cv.z;
        o.w = o0.w * s0.w + o1.w * s1.w + bov + cv.w;
        *(float4*)&out[base] = o;
    }
}

// ---------------------------------------------------------------------------
extern "C" void kernel_launch(void* const* d_in, const int* in_sizes, int n_in,
                              void* d_out, int out_size, void* d_ws, size_t ws_size,
                              hipStream_t stream)
{
    const float* content = (const float*)d_in[0];
    const float* style   = (const float*)d_in[1];
    const float* Wf = (const float*)d_in[2];
    const float* bf = (const float*)d_in[3];
    const float* Wg = (const float*)d_in[4];
    // d_in[5] = bg: provably unused (softmax row-constant)
    const float* Wh = (const float*)d_in[6];
    const float* bh = (const float*)d_in[7];
    const float* Wo = (const float*)d_in[8];
    const float* bo = (const float*)d_in[9];
    float* out = (float*)d_out;
    char* ws = (char*)d_ws;

    stats_kernel<<<4096, 256, 0, stream>>>(content, style, ws);
    transpose_kernel<<<4096, 256, 0, stream>>>(content, style, ws);
    precompute_kernel<<<522, 256, 0, stream>>>(Wf, Wg, Wo, Wh, bf, bh, ws);
    precompute_v_kernel<<<64, 256, 0, stream>>>(Wg, ws);
    prep_gemm_kernel<<<1024, 256, 0, stream>>>(ws);
    t_kernel<<<512, 256, 0, stream>>>(ws);
    flash_split_kernel<<<1024, 256, 0, stream>>>(out, ws);
    combine_kernel<<<256, 256, 0, stream>>>(content, bo, out, ws);
}

// Round 4
// 874.097 us; speedup vs baseline: 1.2919x; 1.2919x over previous
//
#include <hip/hip_runtime.h>

#define C 512
#define HW 4096
#define EPSV 1e-5f

typedef _Float16 fp16x8 __attribute__((ext_vector_type(8)));
typedef _Float16 fp16x4 __attribute__((ext_vector_type(4)));
typedef float f32x4 __attribute__((ext_vector_type(4)));

// ---- workspace layout (bytes) ----
#define OFF_MC    (0)
#define OFF_RC    (8192)
#define OFF_MS    (16384)
#define OFF_RS    (24576)
#define OFF_BETAF (32768)
#define OFF_V     (40960)
#define OFF_BZ    (49152)
#define OFF_T     (65536)                      // t[b][m] f32, 64 KB
#define OFF_SP    (131072)                     // stats partials float2[2][4][512][64] = 2 MB
#define OFF_A     (OFF_SP + 2097152)           // 1 MB
#define OFF_WZ    (OFF_A + 1048576)            // 1 MB
#define OFF_XCT   (OFF_WZ + 1048576)           // 16 MB
#define OFF_XST   (OFF_XCT + 16777216)         // 16 MB
#define OFF_KT    (OFF_XST + 16777216)         // 16 MB
#define OFF_HM    (OFF_KT + 16777216)          // 16 MB
#define OFF_ML    (OFF_HM + 16777216)          // float2[4][4096][64] = 8 MB
#define OFF_SCL   (OFF_ML + 8388608)           // f32 [4][4096][64] = 4 MB
#define OFF_S     (OFF_SCL + 4194304)          // f16 [4][4096][4096] = 128 MB
// total ~= 208 MB

// ---------------------------------------------------------------------------
// 1) fused transpose + f16 cast + partial stats (single read of fp32 input)
//    x[b][c][n] fp32 -> xT[b][n][c] f16 ; per (tensor,b,c,nblk) partial (S, SS)
// ---------------------------------------------------------------------------
__global__ void transpose_stats_kernel(const float* __restrict__ xc, const float* __restrict__ xs,
                                       char* __restrict__ ws)
{
    int bx = blockIdx.x;                  // 4096 = 2 * 4 * 8 * 64
    int tensor = bx >> 11, b = (bx >> 9) & 3, c0 = ((bx >> 6) & 7) * 64, n0 = (bx & 63) * 64;
    const float* src = tensor ? xs : xc;
    _Float16* dst = (_Float16*)(ws + (tensor ? OFF_XST : OFF_XCT));
    float2* part = (float2*)(ws + OFF_SP);

    __shared__ _Float16 tile[64][72];
    __shared__ float sred[4][64], ssred[4][64];

    int tid = threadIdx.x, cR = tid & 63, ng = tid >> 6;
    const float* p = src + ((size_t)(b * C + c0 + cR)) * HW + n0 + ng * 16;
    float s = 0.f, ss = 0.f;
    #pragma unroll
    for (int k = 0; k < 4; k++) {
        float4 v = *(const float4*)(p + k * 4);
        s += v.x + v.y + v.z + v.w;
        ss += v.x * v.x + v.y * v.y + v.z * v.z + v.w * v.w;
        int n = ng * 16 + k * 4;
        tile[n][cR] = (_Float16)v.x; tile[n + 1][cR] = (_Float16)v.y;
        tile[n + 2][cR] = (_Float16)v.z; tile[n + 3][cR] = (_Float16)v.w;
    }
    sred[ng][cR] = s; ssred[ng][cR] = ss;
    __syncthreads();
    if (tid < 64) {
        float S = sred[0][tid] + sred[1][tid] + sred[2][tid] + sred[3][tid];
        float SS = ssred[0][tid] + ssred[1][tid] + ssred[2][tid] + ssred[3][tid];
        part[((size_t)((tensor * 4 + b) * 512 + c0 + tid)) * 64 + (n0 >> 6)] = make_float2(S, SS);
    }
    #pragma unroll
    for (int i = 0; i < 2; i++) {
        int g = tid + i * 256, row = g >> 3, c8 = (g & 7) * 8;
        *(fp16x8*)&dst[((size_t)(b * HW + n0 + row)) * C + c0 + c8] = *(const fp16x8*)&tile[row][c8];
    }
}

// ---------------------------------------------------------------------------
// 1b) finalize stats: reduce 64 partials per channel -> mean / rstd
// ---------------------------------------------------------------------------
__global__ void finalize_stats_kernel(char* __restrict__ ws)
{
    int ch = blockIdx.x * 256 + threadIdx.x;       // 16 blocks -> 4096 channels
    const float2* part = (const float2*)(ws + OFF_SP) + (size_t)ch * 64;
    float S = 0.f, SS = 0.f;
    for (int k = 0; k < 64; k++) { float2 v = part[k]; S += v.x; SS += v.y; }
    int tensor = ch >> 11, rem = ch & 2047;
    float m = S / (float)HW;
    float var = (SS - S * m) / (float)(HW - 1) + EPSV;   // unbiased (n-1) + EPS
    ((float*)(ws + (tensor ? OFF_MS : OFF_MC)))[rem] = m;
    ((float*)(ws + (tensor ? OFF_RS : OFF_RC)))[rem] = rsqrtf(var);
}

// ---------------------------------------------------------------------------
// 2) small precomputes: A = Wf^T Wg, Wz = Wo Wh, betaf, bz = Wo bh
// ---------------------------------------------------------------------------
__global__ void precompute_kernel(const float* __restrict__ Wf, const float* __restrict__ Wg,
                                  const float* __restrict__ Wo, const float* __restrict__ Wh,
                                  const float* __restrict__ bf, const float* __restrict__ bh,
                                  char* __restrict__ ws)
{
    float* A = (float*)(ws + OFF_A);
    float* Wz = (float*)(ws + OFF_WZ);
    float* betaf = (float*)(ws + OFF_BETAF);
    float* bz = (float*)(ws + OFF_BZ);
    const float* mc = (const float*)(ws + OFF_MC);
    const float* rc = (const float*)(ws + OFF_RC);
    int bx = blockIdx.x, t = threadIdx.x;
    if (bx < 512) {                              // A or Wz, 2 output rows per block
        bool isA = bx < 256;
        int r0 = (isA ? bx : bx - 256) * 2;
        float a00 = 0.f, a01 = 0.f, a10 = 0.f, a11 = 0.f;
        for (int k = 0; k < C; k++) {
            float r0v, r1v, c0v, c1v;
            if (isA) {                           // A[i][j] = sum_co Wf[co][i]*Wg[co][j]
                r0v = Wf[k * C + r0]; r1v = Wf[k * C + r0 + 1];
                c0v = Wg[k * C + t];  c1v = Wg[k * C + t + 256];
            } else {                             // Wz[o][j] = sum_i Wo[o][i]*Wh[i][j]
                r0v = Wo[r0 * C + k]; r1v = Wo[(r0 + 1) * C + k];
                c0v = Wh[k * C + t];  c1v = Wh[k * C + t + 256];
            }
            a00 += r0v * c0v; a01 += r0v * c1v;
            a10 += r1v * c0v; a11 += r1v * c1v;
        }
        float* D = isA ? A : Wz;
        D[r0 * C + t] = a00;       D[r0 * C + t + 256] = a01;
        D[(r0 + 1) * C + t] = a10; D[(r0 + 1) * C + t + 256] = a11;
    } else if (bx < 520) {                       // betaf[b][co] = bf[co] - sum_i Wf[co][i]*mc*rc
        int g = (bx - 512) * 256 + t, b = g >> 9, co = g & 511;
        float acc = 0.f;
        for (int i = 0; i < C; i++) acc += Wf[co * C + i] * mc[b * C + i] * rc[b * C + i];
        betaf[g] = bf[co] - acc;
    } else {                                     // bz[co] = sum_i Wo[co][i]*bh[i]
        int co = (bx - 520) * 256 + t;
        float acc = 0.f;
        for (int i = 0; i < C; i++) acc += Wo[co * C + i] * bh[i];
        bz[co] = acc;
    }
}

// v[b][j] = rs[b][j] * sum_co betaf[b][co]*Wg[co][j]   (64 blocks, 8 lanes/output)
__global__ void precompute_v_kernel(const float* __restrict__ Wg, char* __restrict__ ws)
{
    const float* betaf = (const float*)(ws + OFF_BETAF);
    const float* rs = (const float*)(ws + OFF_RS);
    float* v = (float*)(ws + OFF_V);
    int g = blockIdx.x * 32 + (threadIdx.x >> 3);   // 0..2047 output index
    int b = g >> 9, j = g & 511, cq = threadIdx.x & 7;
    float acc = 0.f;
    for (int co = cq * 64; co < cq * 64 + 64; co++) acc += betaf[b * C + co] * Wg[co * C + j];
    acc += __shfl_xor(acc, 1);
    acc += __shfl_xor(acc, 2);
    acc += __shfl_xor(acc, 4);
    if (cq == 0) v[g] = rs[b * C + j] * acc;
}

// ---------------------------------------------------------------------------
// 3) fused prep GEMM:
//    rows 0..511   : Kt[b][m][c] = (diag(rc) A diag(rs) @ xs)[c][m]   (transposed, f16)
//    rows 512..1023: Hm[b][co][m] = (Wz @ xs)[co][m] + bz[co]         (f16)
// ---------------------------------------------------------------------------
__global__ void __launch_bounds__(256) prep_gemm_kernel(char* __restrict__ ws)
{
    const float* A = (const float*)(ws + OFF_A);
    const float* Wz = (const float*)(ws + OFF_WZ);
    const float* rc = (const float*)(ws + OFF_RC);
    const float* rs = (const float*)(ws + OFF_RS);
    const float* bz = (const float*)(ws + OFF_BZ);
    const _Float16* __restrict__ xsT = (const _Float16*)(ws + OFF_XST);
    _Float16* __restrict__ Kt = (_Float16*)(ws + OFF_KT);
    _Float16* __restrict__ Hm = (_Float16*)(ws + OFF_HM);

    int bx = blockIdx.x;                 // 1024 = 4b * 8 rowblk * 32 mblk
    int b = bx & 3, rest = bx >> 2;
    int r128 = rest >> 5, mb = rest & 31;
    int r0 = r128 * 128, m0 = mb * 128;
    int w = threadIdx.x >> 6, lane = threadIdx.x & 63, q = lane >> 4, l16 = lane & 15;
    int wr = (w & 1) * 64, wm = (w >> 1) * 64;
    bool isK = (r0 < 512);
    const float* Asrc = isK ? A : Wz;
    int rbase = (isK ? r0 : r0 - 512) + wr;

    f32x4 zz = {0.f, 0.f, 0.f, 0.f};
    f32x4 acc[4][4];
    #pragma unroll
    for (int rt = 0; rt < 4; rt++)
        #pragma unroll
        for (int mt = 0; mt < 4; mt++) acc[rt][mt] = zz;

    float rcv[4];
    #pragma unroll
    for (int rt = 0; rt < 4; rt++)
        rcv[rt] = isK ? rc[b * C + rbase + rt * 16 + l16] : 1.f;

    for (int ks = 0; ks < 16; ks++) {
        int j0 = ks * 32 + q * 8;
        float rsv[8];
        if (isK) {
            float4 u0 = *(const float4*)&rs[b * C + j0];
            float4 u1 = *(const float4*)&rs[b * C + j0 + 4];
            rsv[0] = u0.x; rsv[1] = u0.y; rsv[2] = u0.z; rsv[3] = u0.w;
            rsv[4] = u1.x; rsv[5] = u1.y; rsv[6] = u1.z; rsv[7] = u1.w;
        } else {
            #pragma unroll
            for (int jj = 0; jj < 8; jj++) rsv[jj] = 1.f;
        }
        fp16x8 afr[4];
        #pragma unroll
        for (int rt = 0; rt < 4; rt++) {
            int row = rbase + rt * 16 + l16;
            float4 a0 = *(const float4*)&Asrc[row * C + j0];
            float4 a1 = *(const float4*)&Asrc[row * C + j0 + 4];
            float av8[8];
            av8[0] = a0.x; av8[1] = a0.y; av8[2] = a0.z; av8[3] = a0.w;
            av8[4] = a1.x; av8[5] = a1.y; av8[6] = a1.z; av8[7] = a1.w;
            float sc = rcv[rt];
            #pragma unroll
            for (int jj = 0; jj < 8; jj++)
                afr[rt][jj] = (_Float16)(isK ? av8[jj] * sc * rsv[jj] : av8[jj]);
        }
        fp16x8 bfr[4];
        #pragma unroll
        for (int mt = 0; mt < 4; mt++)
            bfr[mt] = *(const fp16x8*)&xsT[((size_t)(b * HW + m0 + wm + mt * 16 + l16)) * C + j0];
        #pragma unroll
        for (int rt = 0; rt < 4; rt++)
            #pragma unroll
            for (int mt = 0; mt < 4; mt++)
                acc[rt][mt] = __builtin_amdgcn_mfma_f32_16x16x32_f16(afr[rt], bfr[mt], acc[rt][mt], 0, 0, 0);
    }

    if (isK) {
        #pragma unroll
        for (int rt = 0; rt < 4; rt++)
            #pragma unroll
            for (int mt = 0; mt < 4; mt++) {
                int m = m0 + wm + mt * 16 + l16;
                int cb = r0 + wr + rt * 16 + q * 4;
                fp16x4 h;
                h[0] = (_Float16)acc[rt][mt][0]; h[1] = (_Float16)acc[rt][mt][1];
                h[2] = (_Float16)acc[rt][mt][2]; h[3] = (_Float16)acc[rt][mt][3];
                *(fp16x4*)&Kt[((size_t)(b * HW + m)) * C + cb] = h;
            }
    } else {
        #pragma unroll
        for (int rt = 0; rt < 4; rt++) {
            float bzv[4];
            #pragma unroll
            for (int reg = 0; reg < 4; reg++) bzv[reg] = bz[rbase + rt * 16 + q * 4 + reg];
            #pragma unroll
            for (int mt = 0; mt < 4; mt++) {
                int m = m0 + wm + mt * 16 + l16;
                #pragma unroll
                for (int reg = 0; reg < 4; reg++) {
                    int co = rbase + rt * 16 + q * 4 + reg;
                    Hm[((size_t)(b * C + co)) * HW + m] = (_Float16)(acc[rt][mt][reg] + bzv[reg]);
                }
            }
        }
    }
}

// ---------------------------------------------------------------------------
// 4) t[b][m] = sum_j v[b][j] * xsT[b][m][j]   (per-key softmax bias)
// ---------------------------------------------------------------------------
__global__ void t_kernel(char* __restrict__ ws)
{
    const float* v = (const float*)(ws + OFF_V);
    const _Float16* __restrict__ xsT = (const _Float16*)(ws + OFF_XST);
    float* tG = (float*)(ws + OFF_T);
    int bx = blockIdx.x;                      // 512 = 4 b * 128 mchunks(32)
    int b = bx >> 7, m0 = (bx & 127) * 32;
    int m = m0 + (threadIdx.x >> 3), cq = threadIdx.x & 7;
    const _Float16* p = xsT + ((size_t)(b * HW + m)) * C + cq * 64;
    const float* vp = v + b * C + cq * 64;
    float acc = 0.f;
    #pragma unroll
    for (int k = 0; k < 8; k++) {
        fp16x8 xv = *(const fp16x8*)(p + k * 8);
        float4 v0 = *(const float4*)(vp + k * 8);
        float4 v1 = *(const float4*)(vp + k * 8 + 4);
        acc += (float)xv[0] * v0.x + (float)xv[1] * v0.y + (float)xv[2] * v0.z + (float)xv[3] * v0.w
             + (float)xv[4] * v1.x + (float)xv[5] * v1.y + (float)xv[6] * v1.z + (float)xv[7] * v1.w;
    }
    acc += __shfl_xor(acc, 1);
    acc += __shfl_xor(acc, 2);
    acc += __shfl_xor(acc, 4);
    if (cq == 0) tG[b * HW + m] = acc;
}

// ---------------------------------------------------------------------------
// 5) pass A: S-tile = Q @ Kt^T (128x128, K=512) + t[m]; per-(row, 64-m-tile)
//    max & sumexp; stores p = exp(s - tilemax) f16 to S, (max,sum) to ML.
// ---------------------------------------------------------------------------
__global__ void __launch_bounds__(256, 2) qk_kernel(char* __restrict__ ws)
{
    const _Float16* __restrict__ xcT = (const _Float16*)(ws + OFF_XCT);
    const _Float16* __restrict__ Kt = (const _Float16*)(ws + OFF_KT);
    const float* __restrict__ tG = (const float*)(ws + OFF_T);
    float2* __restrict__ ML = (float2*)(ws + OFF_ML);
    _Float16* __restrict__ Sg = (_Float16*)(ws + OFF_S);

    int bx = blockIdx.x;                  // 4096: low3 = b*2+mhi (XCD-pinned)
    int b = (bx >> 1) & 3, mhi = bx & 1;
    int rest = bx >> 3, mlo = rest & 15, ntile = rest >> 4;
    int m0 = (mhi * 16 + mlo) * 128, n0 = ntile * 128;
    int tid = threadIdx.x, w = tid >> 6, lane = tid & 63, q = lane >> 4, l16 = lane & 15;
    int wn = (w & 1) * 64, wm = (w >> 1) * 64;

    const _Float16* ab = xcT + ((size_t)(b * HW + n0 + wn + l16)) * C;
    const _Float16* bb = Kt + ((size_t)(b * HW + m0 + wm + l16)) * C;

    f32x4 zz = {0.f, 0.f, 0.f, 0.f};
    f32x4 acc[4][4];
    #pragma unroll
    for (int nt = 0; nt < 4; nt++)
        #pragma unroll
        for (int mt = 0; mt < 4; mt++) acc[nt][mt] = zz;

    #pragma unroll 4
    for (int ks = 0; ks < 16; ks++) {
        int k = ks * 32 + q * 8;
        fp16x8 afr[4], bfr[4];
        #pragma unroll
        for (int nt = 0; nt < 4; nt++) afr[nt] = *(const fp16x8*)(ab + (size_t)nt * 16 * C + k);
        #pragma unroll
        for (int mt = 0; mt < 4; mt++) bfr[mt] = *(const fp16x8*)(bb + (size_t)mt * 16 * C + k);
        #pragma unroll
        for (int nt = 0; nt < 4; nt++)
            #pragma unroll
            for (int mt = 0; mt < 4; mt++)
                acc[nt][mt] = __builtin_amdgcn_mfma_f32_16x16x32_f16(afr[nt], bfr[mt], acc[nt][mt], 0, 0, 0);
    }

    // ---- epilogue: + t[m], per-row tile max / exp / sum ----
    float tv[4];
    #pragma unroll
    for (int mt = 0; mt < 4; mt++) tv[mt] = tG[b * HW + m0 + wm + mt * 16 + l16];
    #pragma unroll
    for (int nt = 0; nt < 4; nt++)
        #pragma unroll
        for (int mt = 0; mt < 4; mt++)
            #pragma unroll
            for (int reg = 0; reg < 4; reg++) acc[nt][mt][reg] += tv[mt];

    float rm[4][4], sum[4][4];
    #pragma unroll
    for (int nt = 0; nt < 4; nt++)
        #pragma unroll
        for (int reg = 0; reg < 4; reg++)
            rm[nt][reg] = fmaxf(fmaxf(acc[nt][0][reg], acc[nt][1][reg]),
                                fmaxf(acc[nt][2][reg], acc[nt][3][reg]));
    #pragma unroll
    for (int s = 1; s < 16; s <<= 1)
        #pragma unroll
        for (int nt = 0; nt < 4; nt++)
            #pragma unroll
            for (int reg = 0; reg < 4; reg++)
                rm[nt][reg] = fmaxf(rm[nt][reg], __shfl_xor(rm[nt][reg], s));
    #pragma unroll
    for (int nt = 0; nt < 4; nt++)
        #pragma unroll
        for (int reg = 0; reg < 4; reg++) sum[nt][reg] = 0.f;
    #pragma unroll
    for (int nt = 0; nt < 4; nt++)
        #pragma unroll
        for (int mt = 0; mt < 4; mt++)
            #pragma unroll
            for (int reg = 0; reg < 4; reg++) {
                float pv = __expf(acc[nt][mt][reg] - rm[nt][reg]);
                acc[nt][mt][reg] = pv;
                sum[nt][reg] += pv;
            }
    #pragma unroll
    for (int s = 1; s < 16; s <<= 1)
        #pragma unroll
        for (int nt = 0; nt < 4; nt++)
            #pragma unroll
            for (int reg = 0; reg < 4; reg++)
                sum[nt][reg] += __shfl_xor(sum[nt][reg], s);

    int tl = (m0 + wm) >> 6;
    if (l16 == 0) {
        #pragma unroll
        for (int nt = 0; nt < 4; nt++)
            #pragma unroll
            for (int reg = 0; reg < 4; reg++)
                ML[((size_t)(b * HW + n0 + wn + nt * 16 + q * 4 + reg)) * 64 + tl] =
                    make_float2(rm[nt][reg], sum[nt][reg]);
    }

    // ---- f16 + LDS transpose-spill, then coalesced 16B stores to S ----
    __shared__ _Float16 Pl[4][64][72];
    #pragma unroll
    for (int nt = 0; nt < 4; nt++)
        #pragma unroll
        for (int mt = 0; mt < 4; mt++)
            #pragma unroll
            for (int reg = 0; reg < 4; reg++)
                Pl[w][nt * 16 + q * 4 + reg][mt * 16 + l16] = (_Float16)acc[nt][mt][reg];
    __syncthreads();
    #pragma unroll
    for (int i = 0; i < 8; i++) {
        int row = i * 8 + (lane >> 3), c8 = (lane & 7) * 8;
        *(fp16x8*)&Sg[((size_t)(b * HW + n0 + wn + row)) * HW + m0 + wm + c8] =
            *(const fp16x8*)&Pl[w][row][c8];
    }
}

// ---------------------------------------------------------------------------
// 6) pass B: per row: M = max_t, L = sum_t sum*exp(max_t-M);
//    scale[row][t] = exp(max_t - M)/L
// ---------------------------------------------------------------------------
__global__ void reduce_ml_kernel(char* __restrict__ ws)
{
    const float2* __restrict__ ML = (const float2*)(ws + OFF_ML);
    float* __restrict__ SCL = (float*)(ws + OFF_SCL);
    int w = threadIdx.x >> 6, lane = threadIdx.x & 63;
    size_t row = (size_t)blockIdx.x * 4 + w;       // 4096 blocks -> 16384 rows
    float2 p = ML[row * 64 + lane];
    float M = p.x;
    #pragma unroll
    for (int s = 32; s > 0; s >>= 1) M = fmaxf(M, __shfl_xor(M, s));
    float e = __expf(p.x - M);
    float L = p.y * e;
    #pragma unroll
    for (int s = 32; s > 0; s >>= 1) L += __shfl_xor(L, s);
    SCL[row * 64 + lane] = e / L;
}

// ---------------------------------------------------------------------------
// 7) pass C: O[n][co] = sum_m (p*scale) @ Hm^T  (128x128 tile, K=4096)
//    epilogue: + bo + content
// ---------------------------------------------------------------------------
__global__ void __launch_bounds__(256, 2) pv_kernel(const float* __restrict__ xc,
                                                    const float* __restrict__ bo,
                                                    float* __restrict__ out,
                                                    char* __restrict__ ws)
{
    const _Float16* __restrict__ Sg = (const _Float16*)(ws + OFF_S);
    const _Float16* __restrict__ Hm = (const _Float16*)(ws + OFF_HM);
    const float* __restrict__ SCL = (const float*)(ws + OFF_SCL);

    int bx = blockIdx.x;                  // 512: low3 = b*2+colo (XCD-pinned)
    int b = (bx >> 1) & 3, colo = bx & 1, cohi = (bx >> 3) & 1, ntile = bx >> 4;
    int co0 = (cohi * 2 + colo) * 128, n0 = ntile * 128;
    int tid = threadIdx.x, w = tid >> 6, lane = tid & 63, q = lane >> 4, l16 = lane & 15;
    int wn = (w & 1) * 64, wc = (w >> 1) * 64;

    const _Float16* ab = Sg + ((size_t)(b * HW + n0 + wn + l16)) * HW;
    const _Float16* bb = Hm + ((size_t)(b * C + co0 + wc + l16)) * HW;
    const float* scb = SCL + ((size_t)(b * HW + n0 + wn + l16)) * 64;

    f32x4 zz = {0.f, 0.f, 0.f, 0.f};
    f32x4 acc[4][4];
    #pragma unroll
    for (int nt = 0; nt < 4; nt++)
        #pragma unroll
        for (int ct = 0; ct < 4; ct++) acc[nt][ct] = zz;

    _Float16 sc[4];
    #pragma unroll 2
    for (int km = 0; km < 128; km++) {
        int m = km * 32 + q * 8;
        if ((km & 1) == 0) {
            int tl = km >> 1;
            #pragma unroll
            for (int nt = 0; nt < 4; nt++) sc[nt] = (_Float16)scb[(size_t)nt * 16 * 64 + tl];
        }
        fp16x8 afr[4], bfr[4];
        #pragma unroll
        for (int nt = 0; nt < 4; nt++) {
            afr[nt] = *(const fp16x8*)(ab + (size_t)nt * 16 * HW + m);
            afr[nt] = afr[nt] * sc[nt];
        }
        #pragma unroll
        for (int ct = 0; ct < 4; ct++) bfr[ct] = *(const fp16x8*)(bb + (size_t)ct * 16 * HW + m);
        #pragma unroll
        for (int nt = 0; nt < 4; nt++)
            #pragma unroll
            for (int ct = 0; ct < 4; ct++)
                acc[nt][ct] = __builtin_amdgcn_mfma_f32_16x16x32_f16(afr[nt], bfr[ct], acc[nt][ct], 0, 0, 0);
    }

    #pragma unroll
    for (int nt = 0; nt < 4; nt++)
        #pragma unroll
        for (int ct = 0; ct < 4; ct++) {
            int co = co0 + wc + ct * 16 + l16;
            size_t base = ((size_t)(b * C + co)) * HW + n0 + wn + nt * 16 + q * 4;
            float4 cv = *(const float4*)&xc[base];
            float bov = bo[co];
            float4 o;
            o.x = acc[nt][ct][0] + bov + cv.x;
            o.y = acc[nt][ct][1] + bov + cv.y;
            o.z = acc[nt][ct][2] + bov + cv.z;
            o.w = acc[nt][ct][3] + bov + cv.w;
            *(float4*)&out[base] = o;
        }
}

// ---------------------------------------------------------------------------
extern "C" void kernel_launch(void* const* d_in, const int* in_sizes, int n_in,
                              void* d_out, int out_size, void* d_ws, size_t ws_size,
                              hipStream_t stream)
{
    const float* content = (const float*)d_in[0];
    const float* style   = (const float*)d_in[1];
    const float* Wf = (const float*)d_in[2];
    const float* bf = (const float*)d_in[3];
    const float* Wg = (const float*)d_in[4];
    // d_in[5] = bg: provably unused (softmax row-constant)
    const float* Wh = (const float*)d_in[6];
    const float* bh = (const float*)d_in[7];
    const float* Wo = (const float*)d_in[8];
    const float* bo = (const float*)d_in[9];
    float* out = (float*)d_out;
    char* ws = (char*)d_ws;

    transpose_stats_kernel<<<4096, 256, 0, stream>>>(content, style, ws);
    finalize_stats_kernel<<<16, 256, 0, stream>>>(ws);
    precompute_kernel<<<522, 256, 0, stream>>>(Wf, Wg, Wo, Wh, bf, bh, ws);
    precompute_v_kernel<<<64, 256, 0, stream>>>(Wg, ws);
    prep_gemm_kernel<<<1024, 256, 0, stream>>>(ws);
    t_kernel<<<512, 256, 0, stream>>>(ws);
    qk_kernel<<<4096, 256, 0, stream>>>(ws);
    reduce_ml_kernel<<<4096, 256, 0, stream>>>(ws);
    pv_kernel<<<512, 256, 0, stream>>>(content, bo, out, ws);
}

// Round 5
// 851.944 us; speedup vs baseline: 1.3255x; 1.0260x over previous
//
#include <hip/hip_runtime.h>

#define C 512
#define HW 4096
#define EPSV 1e-5f

typedef _Float16 fp16x8 __attribute__((ext_vector_type(8)));
typedef _Float16 fp16x4 __attribute__((ext_vector_type(4)));
typedef float f32x4 __attribute__((ext_vector_type(4)));

// ---- workspace layout (bytes) ----
#define OFF_MC    (0)
#define OFF_RC    (8192)
#define OFF_MS    (16384)
#define OFF_RS    (24576)
#define OFF_BETAF (32768)
#define OFF_V     (40960)
#define OFF_BZ    (49152)
#define OFF_T     (65536)                      // t[b][m] f32, 64 KB
#define OFF_SP    (131072)                     // stats partials float2[2][4][512][64] = 2 MB
#define OFF_A     (OFF_SP + 2097152)           // 1 MB
#define OFF_WZ    (OFF_A + 1048576)            // 1 MB
#define OFF_XCT   (OFF_WZ + 1048576)           // 16 MB
#define OFF_XST   (OFF_XCT + 16777216)         // 16 MB
#define OFF_KT    (OFF_XST + 16777216)         // 16 MB
#define OFF_HM    (OFF_KT + 16777216)          // 16 MB
#define OFF_ML    (OFF_HM + 16777216)          // float2[4][4096][64] = 8 MB
#define OFF_S     (OFF_ML + 8388608)           // f16 [4][4096][4096] = 128 MB
// total ~= 204 MB

// ---------------------------------------------------------------------------
// 1) fused transpose + f16 cast + partial stats (single read of fp32 input)
// ---------------------------------------------------------------------------
__global__ void transpose_stats_kernel(const float* __restrict__ xc, const float* __restrict__ xs,
                                       char* __restrict__ ws)
{
    int bx = blockIdx.x;                  // 4096 = 2 * 4 * 8 * 64
    int tensor = bx >> 11, b = (bx >> 9) & 3, c0 = ((bx >> 6) & 7) * 64, n0 = (bx & 63) * 64;
    const float* src = tensor ? xs : xc;
    _Float16* dst = (_Float16*)(ws + (tensor ? OFF_XST : OFF_XCT));
    float2* part = (float2*)(ws + OFF_SP);

    __shared__ _Float16 tile[64][72];
    __shared__ float sred[4][64], ssred[4][64];

    int tid = threadIdx.x, cR = tid & 63, ng = tid >> 6;
    const float* p = src + ((size_t)(b * C + c0 + cR)) * HW + n0 + ng * 16;
    float s = 0.f, ss = 0.f;
    #pragma unroll
    for (int k = 0; k < 4; k++) {
        float4 v = *(const float4*)(p + k * 4);
        s += v.x + v.y + v.z + v.w;
        ss += v.x * v.x + v.y * v.y + v.z * v.z + v.w * v.w;
        int n = ng * 16 + k * 4;
        tile[n][cR] = (_Float16)v.x; tile[n + 1][cR] = (_Float16)v.y;
        tile[n + 2][cR] = (_Float16)v.z; tile[n + 3][cR] = (_Float16)v.w;
    }
    sred[ng][cR] = s; ssred[ng][cR] = ss;
    __syncthreads();
    if (tid < 64) {
        float S = sred[0][tid] + sred[1][tid] + sred[2][tid] + sred[3][tid];
        float SS = ssred[0][tid] + ssred[1][tid] + ssred[2][tid] + ssred[3][tid];
        part[((size_t)((tensor * 4 + b) * 512 + c0 + tid)) * 64 + (n0 >> 6)] = make_float2(S, SS);
    }
    #pragma unroll
    for (int i = 0; i < 2; i++) {
        int g = tid + i * 256, row = g >> 3, c8 = (g & 7) * 8;
        *(fp16x8*)&dst[((size_t)(b * HW + n0 + row)) * C + c0 + c8] = *(const fp16x8*)&tile[row][c8];
    }
}

// ---------------------------------------------------------------------------
// 1b) finalize stats
// ---------------------------------------------------------------------------
__global__ void finalize_stats_kernel(char* __restrict__ ws)
{
    int ch = blockIdx.x * 256 + threadIdx.x;       // 16 blocks -> 4096 channels
    const float2* part = (const float2*)(ws + OFF_SP) + (size_t)ch * 64;
    float S = 0.f, SS = 0.f;
    for (int k = 0; k < 64; k++) { float2 v = part[k]; S += v.x; SS += v.y; }
    int tensor = ch >> 11, rem = ch & 2047;
    float m = S / (float)HW;
    float var = (SS - S * m) / (float)(HW - 1) + EPSV;   // unbiased (n-1) + EPS
    ((float*)(ws + (tensor ? OFF_MS : OFF_MC)))[rem] = m;
    ((float*)(ws + (tensor ? OFF_RS : OFF_RC)))[rem] = rsqrtf(var);
}

// ---------------------------------------------------------------------------
// 2) small precomputes: A = Wf^T Wg, Wz = Wo Wh, betaf, bz = Wo bh
// ---------------------------------------------------------------------------
__global__ void precompute_kernel(const float* __restrict__ Wf, const float* __restrict__ Wg,
                                  const float* __restrict__ Wo, const float* __restrict__ Wh,
                                  const float* __restrict__ bf, const float* __restrict__ bh,
                                  char* __restrict__ ws)
{
    float* A = (float*)(ws + OFF_A);
    float* Wz = (float*)(ws + OFF_WZ);
    float* betaf = (float*)(ws + OFF_BETAF);
    float* bz = (float*)(ws + OFF_BZ);
    const float* mc = (const float*)(ws + OFF_MC);
    const float* rc = (const float*)(ws + OFF_RC);
    int bx = blockIdx.x, t = threadIdx.x;
    if (bx < 512) {                              // A or Wz, 2 output rows per block
        bool isA = bx < 256;
        int r0 = (isA ? bx : bx - 256) * 2;
        float a00 = 0.f, a01 = 0.f, a10 = 0.f, a11 = 0.f;
        for (int k = 0; k < C; k++) {
            float r0v, r1v, c0v, c1v;
            if (isA) {                           // A[i][j] = sum_co Wf[co][i]*Wg[co][j]
                r0v = Wf[k * C + r0]; r1v = Wf[k * C + r0 + 1];
                c0v = Wg[k * C + t];  c1v = Wg[k * C + t + 256];
            } else {                             // Wz[o][j] = sum_i Wo[o][i]*Wh[i][j]
                r0v = Wo[r0 * C + k]; r1v = Wo[(r0 + 1) * C + k];
                c0v = Wh[k * C + t];  c1v = Wh[k * C + t + 256];
            }
            a00 += r0v * c0v; a01 += r0v * c1v;
            a10 += r1v * c0v; a11 += r1v * c1v;
        }
        float* D = isA ? A : Wz;
        D[r0 * C + t] = a00;       D[r0 * C + t + 256] = a01;
        D[(r0 + 1) * C + t] = a10; D[(r0 + 1) * C + t + 256] = a11;
    } else if (bx < 520) {                       // betaf[b][co] = bf[co] - sum_i Wf[co][i]*mc*rc
        int g = (bx - 512) * 256 + t, b = g >> 9, co = g & 511;
        float acc = 0.f;
        for (int i = 0; i < C; i++) acc += Wf[co * C + i] * mc[b * C + i] * rc[b * C + i];
        betaf[g] = bf[co] - acc;
    } else {                                     // bz[co] = sum_i Wo[co][i]*bh[i]
        int co = (bx - 520) * 256 + t;
        float acc = 0.f;
        for (int i = 0; i < C; i++) acc += Wo[co * C + i] * bh[i];
        bz[co] = acc;
    }
}

// v[b][j] = rs[b][j] * sum_co betaf[b][co]*Wg[co][j]
__global__ void precompute_v_kernel(const float* __restrict__ Wg, char* __restrict__ ws)
{
    const float* betaf = (const float*)(ws + OFF_BETAF);
    const float* rs = (const float*)(ws + OFF_RS);
    float* v = (float*)(ws + OFF_V);
    int g = blockIdx.x * 32 + (threadIdx.x >> 3);   // 0..2047 output index
    int b = g >> 9, j = g & 511, cq = threadIdx.x & 7;
    float acc = 0.f;
    for (int co = cq * 64; co < cq * 64 + 64; co++) acc += betaf[b * C + co] * Wg[co * C + j];
    acc += __shfl_xor(acc, 1);
    acc += __shfl_xor(acc, 2);
    acc += __shfl_xor(acc, 4);
    if (cq == 0) v[g] = rs[b * C + j] * acc;
}

// ---------------------------------------------------------------------------
// 3) fused prep GEMM -> Kt (transposed, f16) and Hm (f16)
// ---------------------------------------------------------------------------
__global__ void __launch_bounds__(256) prep_gemm_kernel(char* __restrict__ ws)
{
    const float* A = (const float*)(ws + OFF_A);
    const float* Wz = (const float*)(ws + OFF_WZ);
    const float* rc = (const float*)(ws + OFF_RC);
    const float* rs = (const float*)(ws + OFF_RS);
    const float* bz = (const float*)(ws + OFF_BZ);
    const _Float16* __restrict__ xsT = (const _Float16*)(ws + OFF_XST);
    _Float16* __restrict__ Kt = (_Float16*)(ws + OFF_KT);
    _Float16* __restrict__ Hm = (_Float16*)(ws + OFF_HM);

    int bx = blockIdx.x;                 // 1024 = 4b * 8 rowblk * 32 mblk
    int b = bx & 3, rest = bx >> 2;
    int r128 = rest >> 5, mb = rest & 31;
    int r0 = r128 * 128, m0 = mb * 128;
    int w = threadIdx.x >> 6, lane = threadIdx.x & 63, q = lane >> 4, l16 = lane & 15;
    int wr = (w & 1) * 64, wm = (w >> 1) * 64;
    bool isK = (r0 < 512);
    const float* Asrc = isK ? A : Wz;
    int rbase = (isK ? r0 : r0 - 512) + wr;

    f32x4 zz = {0.f, 0.f, 0.f, 0.f};
    f32x4 acc[4][4];
    #pragma unroll
    for (int rt = 0; rt < 4; rt++)
        #pragma unroll
        for (int mt = 0; mt < 4; mt++) acc[rt][mt] = zz;

    float rcv[4];
    #pragma unroll
    for (int rt = 0; rt < 4; rt++)
        rcv[rt] = isK ? rc[b * C + rbase + rt * 16 + l16] : 1.f;

    for (int ks = 0; ks < 16; ks++) {
        int j0 = ks * 32 + q * 8;
        float rsv[8];
        if (isK) {
            float4 u0 = *(const float4*)&rs[b * C + j0];
            float4 u1 = *(const float4*)&rs[b * C + j0 + 4];
            rsv[0] = u0.x; rsv[1] = u0.y; rsv[2] = u0.z; rsv[3] = u0.w;
            rsv[4] = u1.x; rsv[5] = u1.y; rsv[6] = u1.z; rsv[7] = u1.w;
        } else {
            #pragma unroll
            for (int jj = 0; jj < 8; jj++) rsv[jj] = 1.f;
        }
        fp16x8 afr[4];
        #pragma unroll
        for (int rt = 0; rt < 4; rt++) {
            int row = rbase + rt * 16 + l16;
            float4 a0 = *(const float4*)&Asrc[row * C + j0];
            float4 a1 = *(const float4*)&Asrc[row * C + j0 + 4];
            float av8[8];
            av8[0] = a0.x; av8[1] = a0.y; av8[2] = a0.z; av8[3] = a0.w;
            av8[4] = a1.x; av8[5] = a1.y; av8[6] = a1.z; av8[7] = a1.w;
            float sc = rcv[rt];
            #pragma unroll
            for (int jj = 0; jj < 8; jj++)
                afr[rt][jj] = (_Float16)(isK ? av8[jj] * sc * rsv[jj] : av8[jj]);
        }
        fp16x8 bfr[4];
        #pragma unroll
        for (int mt = 0; mt < 4; mt++)
            bfr[mt] = *(const fp16x8*)&xsT[((size_t)(b * HW + m0 + wm + mt * 16 + l16)) * C + j0];
        #pragma unroll
        for (int rt = 0; rt < 4; rt++)
            #pragma unroll
            for (int mt = 0; mt < 4; mt++)
                acc[rt][mt] = __builtin_amdgcn_mfma_f32_16x16x32_f16(afr[rt], bfr[mt], acc[rt][mt], 0, 0, 0);
    }

    if (isK) {
        #pragma unroll
        for (int rt = 0; rt < 4; rt++)
            #pragma unroll
            for (int mt = 0; mt < 4; mt++) {
                int m = m0 + wm + mt * 16 + l16;
                int cb = r0 + wr + rt * 16 + q * 4;
                fp16x4 h;
                h[0] = (_Float16)acc[rt][mt][0]; h[1] = (_Float16)acc[rt][mt][1];
                h[2] = (_Float16)acc[rt][mt][2]; h[3] = (_Float16)acc[rt][mt][3];
                *(fp16x4*)&Kt[((size_t)(b * HW + m)) * C + cb] = h;
            }
    } else {
        #pragma unroll
        for (int rt = 0; rt < 4; rt++) {
            float bzv[4];
            #pragma unroll
            for (int reg = 0; reg < 4; reg++) bzv[reg] = bz[rbase + rt * 16 + q * 4 + reg];
            #pragma unroll
            for (int mt = 0; mt < 4; mt++) {
                int m = m0 + wm + mt * 16 + l16;
                #pragma unroll
                for (int reg = 0; reg < 4; reg++) {
                    int co = rbase + rt * 16 + q * 4 + reg;
                    Hm[((size_t)(b * C + co)) * HW + m] = (_Float16)(acc[rt][mt][reg] + bzv[reg]);
                }
            }
        }
    }
}

// ---------------------------------------------------------------------------
// 4) t[b][m] = sum_j v[b][j] * xsT[b][m][j]
// ---------------------------------------------------------------------------
__global__ void t_kernel(char* __restrict__ ws)
{
    const float* v = (const float*)(ws + OFF_V);
    const _Float16* __restrict__ xsT = (const _Float16*)(ws + OFF_XST);
    float* tG = (float*)(ws + OFF_T);
    int bx = blockIdx.x;                      // 512 = 4 b * 128 mchunks(32)
    int b = bx >> 7, m0 = (bx & 127) * 32;
    int m = m0 + (threadIdx.x >> 3), cq = threadIdx.x & 7;
    const _Float16* p = xsT + ((size_t)(b * HW + m)) * C + cq * 64;
    const float* vp = v + b * C + cq * 64;
    float acc = 0.f;
    #pragma unroll
    for (int k = 0; k < 8; k++) {
        fp16x8 xv = *(const fp16x8*)(p + k * 8);
        float4 v0 = *(const float4*)(vp + k * 8);
        float4 v1 = *(const float4*)(vp + k * 8 + 4);
        acc += (float)xv[0] * v0.x + (float)xv[1] * v0.y + (float)xv[2] * v0.z + (float)xv[3] * v0.w
             + (float)xv[4] * v1.x + (float)xv[5] * v1.y + (float)xv[6] * v1.z + (float)xv[7] * v1.w;
    }
    acc += __shfl_xor(acc, 1);
    acc += __shfl_xor(acc, 2);
    acc += __shfl_xor(acc, 4);
    if (cq == 0) tG[b * HW + m] = acc;
}

// ---------------------------------------------------------------------------
// 5) pass A: S-tile = Q @ Kt^T (128x128, K=512) + t[m]; per-(row, 64-m-tile)
//    max & sumexp; stores p = exp(s - tilemax) f16 to S, (max,sum) to ML.
// ---------------------------------------------------------------------------
__global__ void __launch_bounds__(256, 4) qk_kernel(char* __restrict__ ws)
{
    const _Float16* __restrict__ xcT = (const _Float16*)(ws + OFF_XCT);
    const _Float16* __restrict__ Kt = (const _Float16*)(ws + OFF_KT);
    const float* __restrict__ tG = (const float*)(ws + OFF_T);
    float2* __restrict__ ML = (float2*)(ws + OFF_ML);
    _Float16* __restrict__ Sg = (_Float16*)(ws + OFF_S);

    int bx = blockIdx.x;                  // 4096: low3 = b*2+mhi (XCD-pinned)
    int b = (bx >> 1) & 3, mhi = bx & 1;
    int rest = bx >> 3, mlo = rest & 15, ntile = rest >> 4;
    int m0 = (mhi * 16 + mlo) * 128, n0 = ntile * 128;
    int tid = threadIdx.x, w = tid >> 6, lane = tid & 63, q = lane >> 4, l16 = lane & 15;
    int wn = (w & 1) * 64, wm = (w >> 1) * 64;

    const _Float16* ab = xcT + ((size_t)(b * HW + n0 + wn + l16)) * C;
    const _Float16* bb = Kt + ((size_t)(b * HW + m0 + wm + l16)) * C;

    f32x4 zz = {0.f, 0.f, 0.f, 0.f};
    f32x4 acc[4][4];
    #pragma unroll
    for (int nt = 0; nt < 4; nt++)
        #pragma unroll
        for (int mt = 0; mt < 4; mt++) acc[nt][mt] = zz;

    #pragma unroll 4
    for (int ks = 0; ks < 16; ks++) {
        int k = ks * 32 + q * 8;
        fp16x8 afr[4], bfr[4];
        #pragma unroll
        for (int nt = 0; nt < 4; nt++) afr[nt] = *(const fp16x8*)(ab + (size_t)nt * 16 * C + k);
        #pragma unroll
        for (int mt = 0; mt < 4; mt++) bfr[mt] = *(const fp16x8*)(bb + (size_t)mt * 16 * C + k);
        #pragma unroll
        for (int nt = 0; nt < 4; nt++)
            #pragma unroll
            for (int mt = 0; mt < 4; mt++)
                acc[nt][mt] = __builtin_amdgcn_mfma_f32_16x16x32_f16(afr[nt], bfr[mt], acc[nt][mt], 0, 0, 0);
    }

    // ---- epilogue: + t[m], per-row tile max / exp / sum ----
    float tv[4];
    #pragma unroll
    for (int mt = 0; mt < 4; mt++) tv[mt] = tG[b * HW + m0 + wm + mt * 16 + l16];
    #pragma unroll
    for (int nt = 0; nt < 4; nt++)
        #pragma unroll
        for (int mt = 0; mt < 4; mt++)
            #pragma unroll
            for (int reg = 0; reg < 4; reg++) acc[nt][mt][reg] += tv[mt];

    float rm[4][4], sum[4][4];
    #pragma unroll
    for (int nt = 0; nt < 4; nt++)
        #pragma unroll
        for (int reg = 0; reg < 4; reg++)
            rm[nt][reg] = fmaxf(fmaxf(acc[nt][0][reg], acc[nt][1][reg]),
                                fmaxf(acc[nt][2][reg], acc[nt][3][reg]));
    #pragma unroll
    for (int s = 1; s < 16; s <<= 1)
        #pragma unroll
        for (int nt = 0; nt < 4; nt++)
            #pragma unroll
            for (int reg = 0; reg < 4; reg++)
                rm[nt][reg] = fmaxf(rm[nt][reg], __shfl_xor(rm[nt][reg], s));
    #pragma unroll
    for (int nt = 0; nt < 4; nt++)
        #pragma unroll
        for (int reg = 0; reg < 4; reg++) sum[nt][reg] = 0.f;
    #pragma unroll
    for (int nt = 0; nt < 4; nt++)
        #pragma unroll
        for (int mt = 0; mt < 4; mt++)
            #pragma unroll
            for (int reg = 0; reg < 4; reg++) {
                float pv = __expf(acc[nt][mt][reg] - rm[nt][reg]);
                acc[nt][mt][reg] = pv;
                sum[nt][reg] += pv;
            }
    #pragma unroll
    for (int s = 1; s < 16; s <<= 1)
        #pragma unroll
        for (int nt = 0; nt < 4; nt++)
            #pragma unroll
            for (int reg = 0; reg < 4; reg++)
                sum[nt][reg] += __shfl_xor(sum[nt][reg], s);

    int tl = (m0 + wm) >> 6;
    if (l16 == 0) {
        #pragma unroll
        for (int nt = 0; nt < 4; nt++)
            #pragma unroll
            for (int reg = 0; reg < 4; reg++)
                ML[((size_t)(b * HW + n0 + wn + nt * 16 + q * 4 + reg)) * 64 + tl] =
                    make_float2(rm[nt][reg], sum[nt][reg]);
    }

    // ---- f16 + LDS transpose-spill, then coalesced 16B stores to S ----
    __shared__ _Float16 Pl[4][64][72];
    #pragma unroll
    for (int nt = 0; nt < 4; nt++)
        #pragma unroll
        for (int mt = 0; mt < 4; mt++)
            #pragma unroll
            for (int reg = 0; reg < 4; reg++)
                Pl[w][nt * 16 + q * 4 + reg][mt * 16 + l16] = (_Float16)acc[nt][mt][reg];
    __syncthreads();
    #pragma unroll
    for (int i = 0; i < 8; i++) {
        int row = i * 8 + (lane >> 3), c8 = (lane & 7) * 8;
        *(fp16x8*)&Sg[((size_t)(b * HW + n0 + wn + row)) * HW + m0 + wm + c8] =
            *(const fp16x8*)&Pl[w][row][c8];
    }
}

// ---------------------------------------------------------------------------
// 6) pass C: O = (p * scale) @ Hm^T ; S read ONCE per n-tile (all 256 co of
//    this half), LDS double-buffered 64-key chunks; reduce_ml folded into
//    the prologue (scales in LDS). XCD-pinned: bx&7 = cohalf*4 + b.
// ---------------------------------------------------------------------------
__global__ void __launch_bounds__(1024, 4) pv_kernel(const float* __restrict__ xc,
                                                     const float* __restrict__ bo,
                                                     float* __restrict__ out,
                                                     char* __restrict__ ws)
{
    const _Float16* __restrict__ Sg = (const _Float16*)(ws + OFF_S);
    const _Float16* __restrict__ Hm = (const _Float16*)(ws + OFF_HM);
    const float2* __restrict__ ML = (const float2*)(ws + OFF_ML);

    int bx = blockIdx.x;                  // 256 = 32 ntile * (cohalf*4 + b)
    int b = bx & 3, cohalf = (bx >> 2) & 1, ntile = bx >> 3;
    int n0 = ntile * 128, co0 = cohalf * 256;
    int tid = threadIdx.x, w = tid >> 6, lane = tid & 63, q = lane >> 4, l16 = lane & 15;
    int wn = (w & 3) * 32, wc = (w >> 2) * 64;

    __shared__ _Float16 SclH[64][136];        // [tile][row], f16 scales
    __shared__ _Float16 Al[2][128][72];       // S chunk, 64 keys, padded

    // ---- prologue: per-row global softmax scale (was reduce_ml) ----
    {
        int row = tid >> 3, g = tid & 7;          // 128 rows x 8 lanes
        const float2* mlp = ML + ((size_t)(b * HW + n0 + row)) * 64 + g * 8;
        float2 v[8];
        #pragma unroll
        for (int k = 0; k < 8; k++) v[k] = mlp[k];
        float M = v[0].x;
        #pragma unroll
        for (int k = 1; k < 8; k++) M = fmaxf(M, v[k].x);
        M = fmaxf(M, __shfl_xor(M, 1));
        M = fmaxf(M, __shfl_xor(M, 2));
        M = fmaxf(M, __shfl_xor(M, 4));
        float e[8], L = 0.f;
        #pragma unroll
        for (int k = 0; k < 8; k++) { e[k] = __expf(v[k].x - M); L += v[k].y * e[k]; }
        L += __shfl_xor(L, 1);
        L += __shfl_xor(L, 2);
        L += __shfl_xor(L, 4);
        float linv = 1.f / L;
        #pragma unroll
        for (int k = 0; k < 8; k++) SclH[g * 8 + k][row] = (_Float16)(e[k] * linv);
    }

    // ---- stage chunk 0 (1024 threads cover 128 rows x 64 keys) ----
    int sr = tid >> 3, sc16 = tid & 7;
    const _Float16* sp = Sg + ((size_t)(b * HW + n0 + sr)) * HW + sc16 * 8;
    {
        fp16x8 st = *(const fp16x8*)(sp);
        *(fp16x8*)&Al[0][sr][sc16 * 8] = st;
    }

    f32x4 zz = {0.f, 0.f, 0.f, 0.f};
    f32x4 acc[2][4];
    #pragma unroll
    for (int nt = 0; nt < 2; nt++)
        #pragma unroll
        for (int ct = 0; ct < 4; ct++) acc[nt][ct] = zz;

    const _Float16* hb = Hm + ((size_t)(b * C + co0 + wc + l16)) * HW;

    for (int chunk = 0; chunk < 64; chunk++) {
        int buf = chunk & 1;
        __syncthreads();
        fp16x8 st;
        if (chunk < 63) st = *(const fp16x8*)(sp + (chunk + 1) * 64);

        f32x4 tmp[2][4];
        #pragma unroll
        for (int km = 0; km < 2; km++) {
            int k = km * 32 + q * 8;
            fp16x8 afr[2], bfr[4];
            #pragma unroll
            for (int nt = 0; nt < 2; nt++)
                afr[nt] = *(const fp16x8*)&Al[buf][wn + nt * 16 + l16][k];
            #pragma unroll
            for (int ct = 0; ct < 4; ct++)
                bfr[ct] = *(const fp16x8*)(hb + (size_t)ct * 16 * HW + chunk * 64 + k);
            #pragma unroll
            for (int nt = 0; nt < 2; nt++)
                #pragma unroll
                for (int ct = 0; ct < 4; ct++)
                    tmp[nt][ct] = __builtin_amdgcn_mfma_f32_16x16x32_f16(
                        afr[nt], bfr[ct], km == 0 ? zz : tmp[nt][ct], 0, 0, 0);
        }
        // f32 scale-accumulate: acc += tmp * scale(row, tile=chunk)
        #pragma unroll
        for (int nt = 0; nt < 2; nt++) {
            fp16x4 svh = *(const fp16x4*)&SclH[chunk][wn + nt * 16 + q * 4];
            float sv[4];
            #pragma unroll
            for (int reg = 0; reg < 4; reg++) sv[reg] = (float)svh[reg];
            #pragma unroll
            for (int ct = 0; ct < 4; ct++)
                #pragma unroll
                for (int reg = 0; reg < 4; reg++)
                    acc[nt][ct][reg] += tmp[nt][ct][reg] * sv[reg];
        }
        if (chunk < 63) {
            *(fp16x8*)&Al[buf ^ 1][sr][sc16 * 8] = st;
        }
    }

    // ---- epilogue: + bo + content ----
    #pragma unroll
    for (int nt = 0; nt < 2; nt++)
        #pragma unroll
        for (int ct = 0; ct < 4; ct++) {
            int co = co0 + wc + ct * 16 + l16;
            size_t base = ((size_t)(b * C + co)) * HW + n0 + wn + nt * 16 + q * 4;
            float4 cv = *(const float4*)&xc[base];
            float bov = bo[co];
            float4 o;
            o.x = acc[nt][ct][0] + bov + cv.x;
            o.y = acc[nt][ct][1] + bov + cv.y;
            o.z = acc[nt][ct][2] + bov + cv.z;
            o.w = acc[nt][ct][3] + bov + cv.w;
            *(float4*)&out[base] = o;
        }
}

// ---------------------------------------------------------------------------
extern "C" void kernel_launch(void* const* d_in, const int* in_sizes, int n_in,
                              void* d_out, int out_size, void* d_ws, size_t ws_size,
                              hipStream_t stream)
{
    const float* content = (const float*)d_in[0];
    const float* style   = (const float*)d_in[1];
    const float* Wf = (const float*)d_in[2];
    const float* bf = (const float*)d_in[3];
    const float* Wg = (const float*)d_in[4];
    // d_in[5] = bg: provably unused (softmax row-constant)
    const float* Wh = (const float*)d_in[6];
    const float* bh = (const float*)d_in[7];
    const float* Wo = (const float*)d_in[8];
    const float* bo = (const float*)d_in[9];
    float* out = (float*)d_out;
    char* ws = (char*)d_ws;

    transpose_stats_kernel<<<4096, 256, 0, stream>>>(content, style, ws);
    finalize_stats_kernel<<<16, 256, 0, stream>>>(ws);
    precompute_kernel<<<522, 256, 0, stream>>>(Wf, Wg, Wo, Wh, bf, bh, ws);
    precompute_v_kernel<<<64, 256, 0, stream>>>(Wg, ws);
    prep_gemm_kernel<<<1024, 256, 0, stream>>>(ws);
    t_kernel<<<512, 256, 0, stream>>>(ws);
    qk_kernel<<<4096, 256, 0, stream>>>(ws);
    pv_kernel<<<256, 1024, 0, stream>>>(content, bo, out, ws);
}